// Round 7
// baseline (901.186 us; speedup 1.0000x reference)
//
#include <hip/hip_runtime.h>
#include <hip/hip_bf16.h>

#define NE 8
#define HD 256
#define NT 64
#define NTHREADS 512

typedef __attribute__((ext_vector_type(8))) short short8;
typedef __attribute__((ext_vector_type(4))) float f32x4;

__device__ __forceinline__ unsigned short f2bf(float f) {
    union { float f; unsigned int u; } v; v.f = f;
    return (unsigned short)((v.u + 0x7FFFu + ((v.u >> 16) & 1u)) >> 16);
}
// XOR-swizzled LDS index (element units); keeps 16B chunks aligned and 8B
// groups intact (XOR operand is a multiple of 8 elements).
__device__ __forceinline__ int swz(int row, int col) {
    return row * HD + (col ^ ((row & 7) << 3));
}

// One-time prep: W[e][k][n] fp32 -> Wt[e][n][k] bf16 (contiguous-K A-fragments).
__global__ void prep_weights(const float* __restrict__ W1, const float* __restrict__ W2,
                             unsigned short* __restrict__ W1t, unsigned short* __restrict__ W2t) {
    int idx = blockIdx.x * blockDim.x + threadIdx.x;
    if (idx >= NE * HD * HD) return;
    int nn = idx & 255;          // coalesced read dim
    int kk = (idx >> 8) & 255;
    int e  = idx >> 16;
    W1t[(e * HD + nn) * HD + kk] = f2bf(W1[(e * HD + kk) * HD + nn]);
    W2t[(e * HD + nn) * HD + kk] = f2bf(W2[(e * HD + kk) * HD + nn]);
}

// K-loop, 1-deep pipelined. Wave (wm,wn) owns 64 neurons x 32 points.
// acc[mt][nt]: mt=4 neuron tiles, nt=2 point tiles.
__device__ __forceinline__ void gemm_kloop(
    const unsigned short* Act, const unsigned short* __restrict__ Wt,
    int wm, int wn, int l15, int kg, f32x4 acc[4][2])
{
    #pragma unroll
    for (int mt = 0; mt < 4; ++mt) {
        acc[mt][0] = (f32x4){0.f, 0.f, 0.f, 0.f};
        acc[mt][1] = (f32x4){0.f, 0.f, 0.f, 0.f};
    }
    const int pr0 = wn * 32 + l15;
    const int pr1 = pr0 + 16;
    const unsigned short* Wr = Wt + (wm * 64 + l15) * HD;

    const int k0 = kg * 8;
    short8 af0 = *(const short8*)(Wr + 0 * 16 * HD + k0);
    short8 af1 = *(const short8*)(Wr + 1 * 16 * HD + k0);
    short8 af2 = *(const short8*)(Wr + 2 * 16 * HD + k0);
    short8 af3 = *(const short8*)(Wr + 3 * 16 * HD + k0);
    short8 bf0 = *(const short8*)(Act + swz(pr0, k0));
    short8 bf1 = *(const short8*)(Act + swz(pr1, k0));

    #pragma unroll
    for (int ks = 0; ks < 8; ++ks) {
        short8 naf0, naf1, naf2, naf3, nbf0, nbf1;
        if (ks < 7) {              // prefetch ks+1 while MFMAing ks
            const int k1 = (ks + 1) * 32 + kg * 8;
            naf0 = *(const short8*)(Wr + 0 * 16 * HD + k1);
            naf1 = *(const short8*)(Wr + 1 * 16 * HD + k1);
            naf2 = *(const short8*)(Wr + 2 * 16 * HD + k1);
            naf3 = *(const short8*)(Wr + 3 * 16 * HD + k1);
            nbf0 = *(const short8*)(Act + swz(pr0, k1));
            nbf1 = *(const short8*)(Act + swz(pr1, k1));
        }
        acc[0][0] = __builtin_amdgcn_mfma_f32_16x16x32_bf16(af0, bf0, acc[0][0], 0, 0, 0);
        acc[0][1] = __builtin_amdgcn_mfma_f32_16x16x32_bf16(af0, bf1, acc[0][1], 0, 0, 0);
        acc[1][0] = __builtin_amdgcn_mfma_f32_16x16x32_bf16(af1, bf0, acc[1][0], 0, 0, 0);
        acc[1][1] = __builtin_amdgcn_mfma_f32_16x16x32_bf16(af1, bf1, acc[1][1], 0, 0, 0);
        acc[2][0] = __builtin_amdgcn_mfma_f32_16x16x32_bf16(af2, bf0, acc[2][0], 0, 0, 0);
        acc[2][1] = __builtin_amdgcn_mfma_f32_16x16x32_bf16(af2, bf1, acc[2][1], 0, 0, 0);
        acc[3][0] = __builtin_amdgcn_mfma_f32_16x16x32_bf16(af3, bf0, acc[3][0], 0, 0, 0);
        acc[3][1] = __builtin_amdgcn_mfma_f32_16x16x32_bf16(af3, bf1, acc[3][1], 0, 0, 0);
        af0 = naf0; af1 = naf1; af2 = naf2; af3 = naf3;
        bf0 = nbf0; bf1 = nbf1;
    }
}

__global__ __launch_bounds__(NTHREADS, 4) void moe_fused(
    const float* __restrict__ coords, int npts,
    const float* __restrict__ W0, const float* __restrict__ b0,
    const unsigned short* __restrict__ W1t, const float* __restrict__ b1,
    const unsigned short* __restrict__ W2t, const float* __restrict__ b2,
    const float* __restrict__ W3, const float* __restrict__ b3,
    float* __restrict__ out)
{
    __shared__ __align__(16) unsigned short Act[NT * HD];   // 32 KB
    __shared__ float cbuf[NT * 3];                          // 768 B
    __shared__ float pscr[NT * 4];                          // 1 KB

    const int t = threadIdx.x;
    const int lane = t & 63;
    const int w = t >> 6;
    const int l15 = lane & 15;
    const int kg = lane >> 4;
    const int wm = w >> 1;     // 0..3 neuron group (64 neurons)
    const int wn = w & 1;      // 0..1 point group (32 points)
    const int p0 = blockIdx.x * NT;

    if (t < NT * 3) {
        int idx = p0 * 3 + t;
        int lim = npts * 3 - 1;
        cbuf[t] = coords[idx < lim ? idx : lim];   // clamp: in-bounds, tail masked on store
    }

    // layer-0 mapping: thread owns 2 consecutive neurons x 16 points
    const int j2 = (t & 127) * 2;
    const int prow0 = (t >> 7) * 16;

    float runmax = -3.4e38f;
    f32x4 acc[4][2];

    for (int e = 0; e < NE; ++e) {
        __syncthreads();   // cbuf ready / pscr reads of prev expert done
        // ---- layer 0: 3 -> 256, fp32 VALU, packed b32 writes ----
        {
            const float wx0 = W0[(e*3+0)*HD + j2], wx1 = W0[(e*3+0)*HD + j2+1];
            const float wy0 = W0[(e*3+1)*HD + j2], wy1 = W0[(e*3+1)*HD + j2+1];
            const float wz0 = W0[(e*3+2)*HD + j2], wz1 = W0[(e*3+2)*HD + j2+1];
            const float bb0 = b0[e*HD + j2],       bb1 = b0[e*HD + j2+1];
            #pragma unroll 4
            for (int pp = 0; pp < 16; ++pp) {
                int p = prow0 + pp;
                float x = cbuf[p*3], y = cbuf[p*3+1], z = cbuf[p*3+2];
                float h0 = fmaxf(x*wx0 + y*wy0 + z*wz0 + bb0, 0.f);
                float h1 = fmaxf(x*wx1 + y*wy1 + z*wz1 + bb1, 0.f);
                unsigned int pk = (unsigned int)f2bf(h0) | ((unsigned int)f2bf(h1) << 16);
                *(unsigned int*)(Act + swz(p, j2)) = pk;
            }
        }
        __syncthreads();
        // ---- layer 1 K-loop ----
        gemm_kloop(Act, W1t + e*HD*HD, wm, wn, l15, kg, acc);
        __syncthreads();   // all reads done -> overwrite Act in place
        // ---- layer 1 epilogue: bias+relu, packed 8B writes ----
        #pragma unroll
        for (int mt = 0; mt < 4; ++mt) {
            const int n0 = wm * 64 + mt * 16 + kg * 4;
            const f32x4 bb = *(const f32x4*)(b1 + e*HD + n0);
            #pragma unroll
            for (int nt = 0; nt < 2; ++nt) {
                const int p = wn * 32 + nt * 16 + l15;
                unsigned int lo = (unsigned int)f2bf(fmaxf(acc[mt][nt][0] + bb[0], 0.f))
                                | ((unsigned int)f2bf(fmaxf(acc[mt][nt][1] + bb[1], 0.f)) << 16);
                unsigned int hi = (unsigned int)f2bf(fmaxf(acc[mt][nt][2] + bb[2], 0.f))
                                | ((unsigned int)f2bf(fmaxf(acc[mt][nt][3] + bb[3], 0.f)) << 16);
                *(uint2*)(Act + swz(p, n0)) = make_uint2(lo, hi);
            }
        }
        __syncthreads();
        // ---- layer 2 K-loop ----
        gemm_kloop(Act, W2t + e*HD*HD, wm, wn, l15, kg, acc);
        // ---- fused layer-2 epilogue + layer 3 (fp32, in registers) ----
        {
            const int nb = wm * 64 + kg * 4;
            #pragma unroll
            for (int nt = 0; nt < 2; ++nt) {
                float s = 0.f;
                #pragma unroll
                for (int mt = 0; mt < 4; ++mt) {
                    const f32x4 bb = *(const f32x4*)(b2 + e*HD + nb + mt*16);
                    const f32x4 w3 = *(const f32x4*)(W3 + e*HD + nb + mt*16);
                    #pragma unroll
                    for (int r = 0; r < 4; ++r)
                        s += fmaxf(acc[mt][nt][r] + bb[r], 0.f) * w3[r];
                }
                s += __shfl_xor(s, 16);   // reduce over kg
                s += __shfl_xor(s, 32);
                if (kg == 0) pscr[(wn*32 + nt*16 + l15)*4 + wm] = s;
            }
        }
        __syncthreads();   // pscr ready; also: all L2-kloop Act reads done
        if (t < NT) {
            float s = pscr[t*4] + pscr[t*4+1] + pscr[t*4+2] + pscr[t*4+3];
            runmax = fmaxf(runmax, s + b3[e]);
        }
    }
    if (t < NT) {
        int p = p0 + t;
        if (p < npts) out[p] = runmax;
    }
}

extern "C" void kernel_launch(void* const* d_in, const int* in_sizes, int n_in,
                              void* d_out, int out_size, void* d_ws, size_t ws_size,
                              hipStream_t stream) {
    const float* coords = (const float*)d_in[0];
    const float* W0 = (const float*)d_in[1];
    const float* b0 = (const float*)d_in[2];
    const float* W1 = (const float*)d_in[3];
    const float* b1 = (const float*)d_in[4];
    const float* W2 = (const float*)d_in[5];
    const float* b2 = (const float*)d_in[6];
    const float* W3 = (const float*)d_in[7];
    const float* b3 = (const float*)d_in[8];
    const int npts = in_sizes[0] / 3;

    unsigned short* W1t = (unsigned short*)d_ws;               // 1 MB
    unsigned short* W2t = W1t + NE * HD * HD;                  // 1 MB

    prep_weights<<<(NE * HD * HD + 255) / 256, 256, 0, stream>>>(W1, W2, W1t, W2t);

    int nblocks = (npts + NT - 1) / NT;
    moe_fused<<<nblocks, NTHREADS, 0, stream>>>(
        coords, npts, W0, b0, W1t, b1, W2t, b2, W3, b3, (float*)d_out);
}

// Round 8
// 796.794 us; speedup vs baseline: 1.1310x; 1.1310x over previous
//
#include <hip/hip_runtime.h>
#include <hip/hip_bf16.h>

#define NE 8
#define HD 256
#define NT 64
#define NTHREADS 512

typedef __attribute__((ext_vector_type(8))) short short8;
typedef __attribute__((ext_vector_type(4))) float f32x4;

__device__ __forceinline__ unsigned short f2bf(float f) {
    union { float f; unsigned int u; } v; v.f = f;
    return (unsigned short)((v.u + 0x7FFFu + ((v.u >> 16) & 1u)) >> 16);
}
// XOR-swizzled LDS index (element units); keeps 16B chunks aligned and 8B
// groups intact (XOR operand is a multiple of 8 elements).
__device__ __forceinline__ int swz(int row, int col) {
    return row * HD + (col ^ ((row & 7) << 3));
}

// One-time prep: W[e][k][n] fp32 -> Wt[e][n][k] bf16 (contiguous-K A-fragments).
__global__ void prep_weights(const float* __restrict__ W1, const float* __restrict__ W2,
                             unsigned short* __restrict__ W1t, unsigned short* __restrict__ W2t) {
    int idx = blockIdx.x * blockDim.x + threadIdx.x;
    if (idx >= NE * HD * HD) return;
    int nn = idx & 255;          // coalesced read dim
    int kk = (idx >> 8) & 255;
    int e  = idx >> 16;
    W1t[(e * HD + nn) * HD + kk] = f2bf(W1[(e * HD + kk) * HD + nn]);
    W2t[(e * HD + nn) * HD + kk] = f2bf(W2[(e * HD + kk) * HD + nn]);
}

// K-loop: wave (wm,wn) owns 64 neurons x 32 points. acc[mt 0..3][nt 0..1].
// A (weights) from L2 — disjoint per wm pair; B (act) from LDS, reused 4x.
__device__ __forceinline__ void gemm_kloop(
    const unsigned short* Act, const unsigned short* __restrict__ Wt,
    int wm, int wn, int l15, int kg, f32x4 acc[4][2])
{
    #pragma unroll
    for (int mt = 0; mt < 4; ++mt) {
        acc[mt][0] = (f32x4){0.f, 0.f, 0.f, 0.f};
        acc[mt][1] = (f32x4){0.f, 0.f, 0.f, 0.f};
    }
    const int pr0 = wn * 32 + l15;
    const int pr1 = pr0 + 16;
    const unsigned short* Wr = Wt + (wm * 64 + l15) * HD;

    #pragma unroll
    for (int ks = 0; ks < 8; ++ks) {
        const int k0 = ks * 32 + kg * 8;
        short8 bf0 = *(const short8*)(Act + swz(pr0, k0));   // ds_read_b128
        short8 bf1 = *(const short8*)(Act + swz(pr1, k0));
        #pragma unroll
        for (int mt = 0; mt < 4; ++mt) {
            short8 af = *(const short8*)(Wr + mt * 16 * HD + k0);  // L2-resident
            acc[mt][0] = __builtin_amdgcn_mfma_f32_16x16x32_bf16(af, bf0, acc[mt][0], 0, 0, 0);
            acc[mt][1] = __builtin_amdgcn_mfma_f32_16x16x32_bf16(af, bf1, acc[mt][1], 0, 0, 0);
        }
    }
}

// One expert per block: blockIdx = tile*8 + e. 5 barrier phases total.
__global__ __launch_bounds__(NTHREADS, 4) void moe_expert(
    const float* __restrict__ coords, int npts,
    const float* __restrict__ W0, const float* __restrict__ b0,
    const unsigned short* __restrict__ W1t, const float* __restrict__ b1,
    const unsigned short* __restrict__ W2t, const float* __restrict__ b2,
    const float* __restrict__ W3, const float* __restrict__ b3,
    float* __restrict__ ws)
{
    __shared__ __align__(16) unsigned short Act[NT * HD];   // 32 KB
    __shared__ float cbuf[NT * 3];                          // 768 B
    __shared__ float pscr[NT * 4];                          // 1 KB

    const int t = threadIdx.x;
    const int lane = t & 63;
    const int w = t >> 6;
    const int l15 = lane & 15;
    const int kg = lane >> 4;
    const int wm = w >> 1;     // 0..3: neuron group of 64
    const int wn = w & 1;      // 0..1: point group of 32
    const int e = blockIdx.x & 7;
    const int p0 = (blockIdx.x >> 3) * NT;

    if (t < NT * 3) {
        int idx = p0 * 3 + t;
        int lim = npts * 3 - 1;
        cbuf[t] = coords[idx < lim ? idx : lim];   // clamp: in-bounds, tail masked on store
    }
    __syncthreads();

    // ---- layer 0: 3 -> 256, fp32 VALU, packed b32 writes ----
    {
        const int j2 = (t & 127) * 2;            // 2 consecutive neurons
        const int prow0 = (t >> 7) * 16;         // 16 points
        const float wx0 = W0[(e*3+0)*HD + j2], wx1 = W0[(e*3+0)*HD + j2+1];
        const float wy0 = W0[(e*3+1)*HD + j2], wy1 = W0[(e*3+1)*HD + j2+1];
        const float wz0 = W0[(e*3+2)*HD + j2], wz1 = W0[(e*3+2)*HD + j2+1];
        const float bb0 = b0[e*HD + j2],       bb1 = b0[e*HD + j2+1];
        #pragma unroll 4
        for (int pp = 0; pp < 16; ++pp) {
            int p = prow0 + pp;
            float x = cbuf[p*3], y = cbuf[p*3+1], z = cbuf[p*3+2];
            float h0 = fmaxf(x*wx0 + y*wy0 + z*wz0 + bb0, 0.f);
            float h1 = fmaxf(x*wx1 + y*wy1 + z*wz1 + bb1, 0.f);
            unsigned int pk = (unsigned int)f2bf(h0) | ((unsigned int)f2bf(h1) << 16);
            *(unsigned int*)(Act + swz(p, j2)) = pk;
        }
    }
    __syncthreads();

    f32x4 acc[4][2];
    // ---- layer 1 K-loop ----
    gemm_kloop(Act, W1t + e*HD*HD, wm, wn, l15, kg, acc);
    __syncthreads();   // all reads done -> overwrite Act in place
    // ---- layer 1 epilogue: bias+relu, packed 8B writes ----
    #pragma unroll
    for (int mt = 0; mt < 4; ++mt) {
        const int n0 = wm * 64 + mt * 16 + kg * 4;
        const f32x4 bb = *(const f32x4*)(b1 + e*HD + n0);
        #pragma unroll
        for (int nt = 0; nt < 2; ++nt) {
            const int p = wn * 32 + nt * 16 + l15;
            unsigned int lo = (unsigned int)f2bf(fmaxf(acc[mt][nt][0] + bb[0], 0.f))
                            | ((unsigned int)f2bf(fmaxf(acc[mt][nt][1] + bb[1], 0.f)) << 16);
            unsigned int hi = (unsigned int)f2bf(fmaxf(acc[mt][nt][2] + bb[2], 0.f))
                            | ((unsigned int)f2bf(fmaxf(acc[mt][nt][3] + bb[3], 0.f)) << 16);
            *(uint2*)(Act + swz(p, n0)) = make_uint2(lo, hi);
        }
    }
    __syncthreads();
    // ---- layer 2 K-loop ----
    gemm_kloop(Act, W2t + e*HD*HD, wm, wn, l15, kg, acc);
    // ---- fused layer-2 epilogue + layer 3 (fp32, in registers) ----
    {
        const int nb = wm * 64 + kg * 4;
        #pragma unroll
        for (int nt = 0; nt < 2; ++nt) {
            float s = 0.f;
            #pragma unroll
            for (int mt = 0; mt < 4; ++mt) {
                const f32x4 bb = *(const f32x4*)(b2 + e*HD + nb + mt*16);
                const f32x4 w3 = *(const f32x4*)(W3 + e*HD + nb + mt*16);
                #pragma unroll
                for (int r = 0; r < 4; ++r)
                    s += fmaxf(acc[mt][nt][r] + bb[r], 0.f) * w3[r];
            }
            s += __shfl_xor(s, 16);   // reduce over kg (4 lanes per point)
            s += __shfl_xor(s, 32);
            if (kg == 0) pscr[(wn*32 + nt*16 + l15)*4 + wm] = s;
        }
    }
    __syncthreads();
    if (t < NT) {
        f32x4 v = *(const f32x4*)(pscr + t*4);
        int p = p0 + t;
        if (p < npts) ws[e * npts + p] = v[0] + v[1] + v[2] + v[3] + b3[e];
    }
}

// Max over the 8 experts' partials.
__global__ void moe_reduce(const float* __restrict__ ws, float* __restrict__ out, int npts) {
    int p = blockIdx.x * 256 + threadIdx.x;
    if (p >= npts) return;
    float m = ws[p];
    #pragma unroll
    for (int e = 1; e < NE; ++e) m = fmaxf(m, ws[e * npts + p]);
    out[p] = m;
}

extern "C" void kernel_launch(void* const* d_in, const int* in_sizes, int n_in,
                              void* d_out, int out_size, void* d_ws, size_t ws_size,
                              hipStream_t stream) {
    const float* coords = (const float*)d_in[0];
    const float* W0 = (const float*)d_in[1];
    const float* b0 = (const float*)d_in[2];
    const float* W1 = (const float*)d_in[3];
    const float* b1 = (const float*)d_in[4];
    const float* W2 = (const float*)d_in[5];
    const float* b2 = (const float*)d_in[6];
    const float* W3 = (const float*)d_in[7];
    const float* b3 = (const float*)d_in[8];
    const int npts = in_sizes[0] / 3;

    unsigned short* W1t = (unsigned short*)d_ws;               // 1 MB
    unsigned short* W2t = W1t + NE * HD * HD;                  // 1 MB
    float* eout = (float*)(W2t + NE * HD * HD);                // 8*npts floats

    prep_weights<<<(NE * HD * HD + 255) / 256, 256, 0, stream>>>(W1, W2, W1t, W2t);

    int ntiles = (npts + NT - 1) / NT;
    moe_expert<<<ntiles * NE, NTHREADS, 0, stream>>>(
        coords, npts, W0, b0, W1t, b1, W2t, b2, W3, b3, eout);

    moe_reduce<<<(npts + 255) / 256, 256, 0, stream>>>(eout, (float*)d_out, npts);
}

// Round 9
// 422.609 us; speedup vs baseline: 2.1324x; 1.8854x over previous
//
#include <hip/hip_runtime.h>
#include <hip/hip_bf16.h>

#define NE 8
#define HD 256
#define NT 64
#define NTHREADS 512

typedef __attribute__((ext_vector_type(8))) short short8;
typedef __attribute__((ext_vector_type(4))) float f32x4;

__device__ __forceinline__ unsigned short f2bf(float f) {
    union { float f; unsigned int u; } v; v.f = f;
    return (unsigned short)((v.u + 0x7FFFu + ((v.u >> 16) & 1u)) >> 16);
}
// XOR-swizzled LDS index (element units); keeps 16B chunks aligned and 8B
// groups intact (XOR operand is a multiple of 8 elements).
__device__ __forceinline__ int swz(int row, int col) {
    return row * HD + (col ^ ((row & 7) << 3));
}

// One-time prep: W[e][k][n] fp32 -> Wt[e][n][k] bf16 (contiguous-K A-fragments).
__global__ void prep_weights(const float* __restrict__ W1, const float* __restrict__ W2,
                             unsigned short* __restrict__ W1t, unsigned short* __restrict__ W2t) {
    int idx = blockIdx.x * blockDim.x + threadIdx.x;
    if (idx >= NE * HD * HD) return;
    int nn = idx & 255;          // coalesced read dim
    int kk = (idx >> 8) & 255;
    int e  = idx >> 16;
    W1t[(e * HD + nn) * HD + kk] = f2bf(W1[(e * HD + kk) * HD + nn]);
    W2t[(e * HD + nn) * HD + kk] = f2bf(W2[(e * HD + kk) * HD + nn]);
}

// K-loop (R6 dataflow): wave w owns neurons [w*32, w*32+32) — weight L2 loads
// DISJOINT across waves, only 2 per ks — and iterates ALL 64 points (nt=4).
// Per ks: 2 global 16B + 4 ds_read_b128 + 8 MFMA (TA 256 / LDS 384 / MFMA 320 cy).
__device__ __forceinline__ void gemm_kloop(
    const unsigned short* Act, const unsigned short* __restrict__ Wt,
    int w, int l15, int kg, f32x4 acc[2][4])
{
    #pragma unroll
    for (int mt = 0; mt < 2; ++mt)
        #pragma unroll
        for (int nt = 0; nt < 4; ++nt)
            acc[mt][nt] = (f32x4){0.f, 0.f, 0.f, 0.f};

    const unsigned short* Wt0 = Wt + (w * 32 + l15) * HD;   // mt=0 row
    const unsigned short* Wt1 = Wt0 + 16 * HD;              // mt=1 row

    #pragma unroll
    for (int ks = 0; ks < 8; ++ks) {
        const int k0 = ks * 32 + kg * 8;
        short8 af0 = *(const short8*)(Wt0 + k0);            // L2-resident
        short8 af1 = *(const short8*)(Wt1 + k0);
        #pragma unroll
        for (int nt = 0; nt < 4; ++nt) {
            short8 bf = *(const short8*)(Act + swz(nt * 16 + l15, k0)); // ds_read_b128
            acc[0][nt] = __builtin_amdgcn_mfma_f32_16x16x32_bf16(af0, bf, acc[0][nt], 0, 0, 0);
            acc[1][nt] = __builtin_amdgcn_mfma_f32_16x16x32_bf16(af1, bf, acc[1][nt], 0, 0, 0);
        }
    }
}

// One expert per block: blockIdx = tile*8 + e. 5 barrier phases per block.
__global__ __launch_bounds__(NTHREADS, 4) void moe_expert(
    const float* __restrict__ coords, int npts,
    const float* __restrict__ W0, const float* __restrict__ b0,
    const unsigned short* __restrict__ W1t, const float* __restrict__ b1,
    const unsigned short* __restrict__ W2t, const float* __restrict__ b2,
    const float* __restrict__ W3, const float* __restrict__ b3,
    float* __restrict__ ws)
{
    __shared__ __align__(16) unsigned short Act[NT * HD];   // 32 KB
    __shared__ float cbuf[NT * 3];                          // 768 B
    __shared__ float pscr[NT * 8];                          // 2 KB

    const int t = threadIdx.x;
    const int lane = t & 63;
    const int w = t >> 6;       // 0..7: neuron group of 32
    const int l15 = lane & 15;
    const int kg = lane >> 4;
    const int e = blockIdx.x & 7;
    const int p0 = (blockIdx.x >> 3) * NT;

    if (t < NT * 3) {
        int idx = p0 * 3 + t;
        int lim = npts * 3 - 1;
        cbuf[t] = coords[idx < lim ? idx : lim];   // clamp: in-bounds, tail masked on store
    }
    __syncthreads();

    // ---- layer 0: 3 -> 256, fp32 VALU, packed b32 writes ----
    {
        const int j2 = (t & 127) * 2;            // 2 consecutive neurons
        const int prow0 = (t >> 7) * 16;         // 16 points
        const float wx0 = W0[(e*3+0)*HD + j2], wx1 = W0[(e*3+0)*HD + j2+1];
        const float wy0 = W0[(e*3+1)*HD + j2], wy1 = W0[(e*3+1)*HD + j2+1];
        const float wz0 = W0[(e*3+2)*HD + j2], wz1 = W0[(e*3+2)*HD + j2+1];
        const float bb0 = b0[e*HD + j2],       bb1 = b0[e*HD + j2+1];
        #pragma unroll 4
        for (int pp = 0; pp < 16; ++pp) {
            int p = prow0 + pp;
            float x = cbuf[p*3], y = cbuf[p*3+1], z = cbuf[p*3+2];
            float h0 = fmaxf(x*wx0 + y*wy0 + z*wz0 + bb0, 0.f);
            float h1 = fmaxf(x*wx1 + y*wy1 + z*wz1 + bb1, 0.f);
            unsigned int pk = (unsigned int)f2bf(h0) | ((unsigned int)f2bf(h1) << 16);
            *(unsigned int*)(Act + swz(p, j2)) = pk;
        }
    }
    __syncthreads();

    f32x4 acc[2][4];
    // ---- layer 1 K-loop ----
    gemm_kloop(Act, W1t + e*HD*HD, w, l15, kg, acc);
    __syncthreads();   // all reads done -> overwrite Act in place
    // ---- layer 1 epilogue: bias+relu, packed 8B writes ----
    #pragma unroll
    for (int mt = 0; mt < 2; ++mt) {
        const int n0 = w * 32 + mt * 16 + kg * 4;
        const f32x4 bb = *(const f32x4*)(b1 + e*HD + n0);
        #pragma unroll
        for (int nt = 0; nt < 4; ++nt) {
            const int p = nt * 16 + l15;
            unsigned int lo = (unsigned int)f2bf(fmaxf(acc[mt][nt][0] + bb[0], 0.f))
                            | ((unsigned int)f2bf(fmaxf(acc[mt][nt][1] + bb[1], 0.f)) << 16);
            unsigned int hi = (unsigned int)f2bf(fmaxf(acc[mt][nt][2] + bb[2], 0.f))
                            | ((unsigned int)f2bf(fmaxf(acc[mt][nt][3] + bb[3], 0.f)) << 16);
            *(uint2*)(Act + swz(p, n0)) = make_uint2(lo, hi);
        }
    }
    __syncthreads();
    // ---- layer 2 K-loop ----
    gemm_kloop(Act, W2t + e*HD*HD, w, l15, kg, acc);
    // ---- fused layer-2 epilogue + layer 3 (fp32, in registers) ----
    {
        const int nb = w * 32 + kg * 4;
        const f32x4 bb0 = *(const f32x4*)(b2 + e*HD + nb);
        const f32x4 bb1 = *(const f32x4*)(b2 + e*HD + nb + 16);
        const f32x4 w30 = *(const f32x4*)(W3 + e*HD + nb);
        const f32x4 w31 = *(const f32x4*)(W3 + e*HD + nb + 16);
        #pragma unroll
        for (int nt = 0; nt < 4; ++nt) {
            float s = 0.f;
            #pragma unroll
            for (int r = 0; r < 4; ++r) {
                s += fmaxf(acc[0][nt][r] + bb0[r], 0.f) * w30[r];
                s += fmaxf(acc[1][nt][r] + bb1[r], 0.f) * w31[r];
            }
            s += __shfl_xor(s, 16);   // reduce over kg (4 lanes per point)
            s += __shfl_xor(s, 32);
            if (kg == 0) pscr[(nt * 16 + l15) * 8 + w] = s;  // per-wave partial
        }
    }
    __syncthreads();
    if (t < NT) {
        float s = 0.f;
        #pragma unroll
        for (int j = 0; j < 8; ++j) s += pscr[t * 8 + j];
        int p = p0 + t;
        if (p < npts) ws[e * npts + p] = s + b3[e];
    }
}

// Max over the 8 experts' partials.
__global__ void moe_reduce(const float* __restrict__ ws, float* __restrict__ out, int npts) {
    int p = blockIdx.x * 256 + threadIdx.x;
    if (p >= npts) return;
    float m = ws[p];
    #pragma unroll
    for (int e = 1; e < NE; ++e) m = fmaxf(m, ws[e * npts + p]);
    out[p] = m;
}

extern "C" void kernel_launch(void* const* d_in, const int* in_sizes, int n_in,
                              void* d_out, int out_size, void* d_ws, size_t ws_size,
                              hipStream_t stream) {
    const float* coords = (const float*)d_in[0];
    const float* W0 = (const float*)d_in[1];
    const float* b0 = (const float*)d_in[2];
    const float* W1 = (const float*)d_in[3];
    const float* b1 = (const float*)d_in[4];
    const float* W2 = (const float*)d_in[5];
    const float* b2 = (const float*)d_in[6];
    const float* W3 = (const float*)d_in[7];
    const float* b3 = (const float*)d_in[8];
    const int npts = in_sizes[0] / 3;

    unsigned short* W1t = (unsigned short*)d_ws;               // 1 MB
    unsigned short* W2t = W1t + NE * HD * HD;                  // 1 MB
    float* eout = (float*)(W2t + NE * HD * HD);                // 8*npts floats

    prep_weights<<<(NE * HD * HD + 255) / 256, 256, 0, stream>>>(W1, W2, W1t, W2t);

    int ntiles = (npts + NT - 1) / NT;
    moe_expert<<<ntiles * NE, NTHREADS, 0, stream>>>(
        coords, npts, W0, b0, W1t, b1, W2t, b2, W3, b3, eout);

    moe_reduce<<<(npts + 255) / 256, 256, 0, stream>>>(eout, (float*)d_out, npts);
}